// Round 2
// baseline (280.419 us; speedup 1.0000x reference)
//
#include <hip/hip_runtime.h>
#include <stdint.h>

#define D_DIM 256
#define K_CODES 8192
#define BM 256        // rows per block (4 waves x 64 rows)
#define BN 64         // codes per tile
#define KSPLIT 8      // codebook split across blocks; blockIdx%8 == XCD == slice
#define CPB (K_CODES / KSPLIT)   // 1024 codes per block
#define NT (CPB / BN)            // 16 tiles
#define KT 8                     // D/32 k-steps per MFMA chain

typedef float f32x4 __attribute__((ext_vector_type(4)));
typedef short bf16x8 __attribute__((ext_vector_type(8)));

__device__ __forceinline__ ushort f2bf(float f) {
  uint32_t u = __builtin_bit_cast(uint32_t, f);
  return (ushort)((u + 0x7FFFu + ((u >> 16) & 1u)) >> 16);  // RNE
}

// ---------------------------------------------------------------------------
// prepT: codebook -> bf16 in k-tiled transposed layout.
// cbbT is 32 k-octet planes of [8192 codes x 16B]. Thread o writes 16B at
// cbbT + o*16 (fully coalesced), o = kk*8192 + code.
// ---------------------------------------------------------------------------
__global__ void vq_prepT(const float* __restrict__ cb, uint4* __restrict__ cbbT) {
  const int o = blockIdx.x * 256 + threadIdx.x;     // 0 .. 32*8192-1
  const int kk = o >> 13;                           // k-octet 0..31
  const int code = o & 8191;
  const float4 lo = *(const float4*)(cb + (size_t)code * D_DIM + kk * 8);
  const float4 hi = *(const float4*)(cb + (size_t)code * D_DIM + kk * 8 + 4);
  uint4 v;
  v.x = ((uint32_t)f2bf(lo.y) << 16) | f2bf(lo.x);
  v.y = ((uint32_t)f2bf(lo.w) << 16) | f2bf(lo.z);
  v.z = ((uint32_t)f2bf(hi.y) << 16) | f2bf(hi.x);
  v.w = ((uint32_t)f2bf(hi.w) << 16) | f2bf(hi.z);
  cbbT[o] = v;
}

// squared norms of codebook rows: one wave per code
__global__ void vq_norm(const float* __restrict__ cb, float* __restrict__ cnorm) {
  const int lane = threadIdx.x & 63;
  const int code = (blockIdx.x * blockDim.x + threadIdx.x) >> 6;
  const float4 v = *(const float4*)(cb + (size_t)code * D_DIM + lane * 4);
  float ss = v.x * v.x + v.y * v.y + v.z * v.z + v.w * v.w;
#pragma unroll
  for (int m = 32; m >= 1; m >>= 1) ss += __shfl_xor(ss, m, 64);
  if (lane == 0) cnorm[code] = ss;
}

// ---------------------------------------------------------------------------
// main: fused distance GEMM + argmin, B streamed straight from L2 (no LDS,
// no barriers). Each wave: 64 x-rows in registers, loops its codebook slice.
// Score = ||c||^2 - 2*dot (row term constant -> dropped for argmin).
// ---------------------------------------------------------------------------
__global__ __launch_bounds__(256, 2) void vq_main(
    const float* __restrict__ x, const char* __restrict__ cbbT,
    const float* __restrict__ cnorm, unsigned long long* __restrict__ amin) {
  const int tid = threadIdx.x;
  const int lane = tid & 63;
  const int wid = tid >> 6;
  const int ks = blockIdx.x & (KSPLIT - 1);   // == XCD id -> L2-resident slice
  const int mb = blockIdx.x >> 3;
  const int r0 = mb * BM + wid * 64;

  // A fragments: lane holds row (lane&15) of frag, k = (lane>>4)*8 + [0,8)
  bf16x8 a[4][KT];
#pragma unroll
  for (int rf = 0; rf < 4; rf++) {
    const float* xr =
        x + (size_t)(r0 + rf * 16 + (lane & 15)) * D_DIM + ((lane >> 4) * 8);
#pragma unroll
    for (int t = 0; t < KT; t++) {
      float4 lo = *(const float4*)(xr + t * 32);
      float4 hi = *(const float4*)(xr + t * 32 + 4);
      bf16x8 fr;
      fr[0] = (short)f2bf(lo.x); fr[1] = (short)f2bf(lo.y);
      fr[2] = (short)f2bf(lo.z); fr[3] = (short)f2bf(lo.w);
      fr[4] = (short)f2bf(hi.x); fr[5] = (short)f2bf(hi.y);
      fr[6] = (short)f2bf(hi.z); fr[7] = (short)f2bf(hi.w);
      a[rf][t] = fr;
    }
  }

  float mv[4][4];
  uint32_t mi[4][4];
#pragma unroll
  for (int rf = 0; rf < 4; rf++)
#pragma unroll
    for (int j = 0; j < 4; j++) { mv[rf][j] = 3.4e38f; mi[rf][j] = 0u; }

  // per-lane base into cbbT: kk-half (lane>>4), code-within-16 (lane&15)
  const char* bT = cbbT + (size_t)(lane >> 4) * (K_CODES * 16) + (lane & 15) * 16;

  for (int tile = 0; tile < NT; tile++) {
    const int cbase = ks * CPB + tile * BN;
    float cn[4];
#pragma unroll
    for (int s = 0; s < 4; s++) cn[s] = cnorm[cbase + s * 16 + (lane & 15)];

#pragma unroll
    for (int s = 0; s < 4; s++) {
      const char* p = bT + (size_t)(cbase + s * 16) * 16;
      f32x4 acc0 = {0.f, 0.f, 0.f, 0.f};
      f32x4 acc1 = acc0, acc2 = acc0, acc3 = acc0;
#pragma unroll
      for (int t = 0; t < KT; t++) {
        // kk advances by 4 per t: 4 * 8192 * 16B = 524288B plane stride
        const bf16x8 b = *(const bf16x8*)(p + (size_t)t * (4 * K_CODES * 16));
        acc0 = __builtin_amdgcn_mfma_f32_16x16x32_bf16(a[0][t], b, acc0, 0, 0, 0);
        acc1 = __builtin_amdgcn_mfma_f32_16x16x32_bf16(a[1][t], b, acc1, 0, 0, 0);
        acc2 = __builtin_amdgcn_mfma_f32_16x16x32_bf16(a[2][t], b, acc2, 0, 0, 0);
        acc3 = __builtin_amdgcn_mfma_f32_16x16x32_bf16(a[3][t], b, acc3, 0, 0, 0);
      }
      const uint32_t col = (uint32_t)(cbase + s * 16 + (lane & 15));
#pragma unroll
      for (int j = 0; j < 4; j++) {
        float sc;
        sc = fmaf(-2.f, acc0[j], cn[s]);
        if (sc < mv[0][j]) { mv[0][j] = sc; mi[0][j] = col; }
        sc = fmaf(-2.f, acc1[j], cn[s]);
        if (sc < mv[1][j]) { mv[1][j] = sc; mi[1][j] = col; }
        sc = fmaf(-2.f, acc2[j], cn[s]);
        if (sc < mv[2][j]) { mv[2][j] = sc; mi[2][j] = col; }
        sc = fmaf(-2.f, acc3[j], cn[s]);
        if (sc < mv[3][j]) { mv[3][j] = sc; mi[3][j] = col; }
      }
    }
  }

  // reduce across the 16 lanes holding the same rows; acc row = (lane>>4)*4+j
#pragma unroll
  for (int rf = 0; rf < 4; rf++) {
#pragma unroll
    for (int j = 0; j < 4; j++) {
      uint32_t fb = __builtin_bit_cast(uint32_t, mv[rf][j]);
      fb = (fb & 0x80000000u) ? ~fb : (fb | 0x80000000u);  // orderable uint
      unsigned long long p =
          ((unsigned long long)fb << 32) | (unsigned long long)mi[rf][j];
#pragma unroll
      for (int m = 1; m < 16; m <<= 1) {
        unsigned long long q = __shfl_xor(p, m, 64);
        p = (q < p) ? q : p;
      }
      if ((lane & 15) == 0) {
        const int row = r0 + rf * 16 + (lane >> 4) * 4 + j;
        atomicMin(&amin[row], p);  // order-independent -> deterministic
      }
    }
  }
}

// ---------------------------------------------------------------------------
// gather: x_q = codebook[argmin], L1 loss partial (fixed-point, deterministic)
// ---------------------------------------------------------------------------
__global__ void vq_gather(const float* __restrict__ x, const float* __restrict__ cb,
                          const unsigned long long* __restrict__ amin,
                          float* __restrict__ out,
                          unsigned long long* __restrict__ lossacc) {
  const int lane = threadIdx.x & 63;
  const int wid = threadIdx.x >> 6;
  const int row0 = blockIdx.x * 64 + wid * 16;
  float lsum = 0.f;
  for (int r = 0; r < 16; r++) {
    const int row = row0 + r;
    const uint32_t idx = (uint32_t)(amin[row] & 0xFFFFFFFFull);
    const float4 e = *(const float4*)(cb + (size_t)idx * D_DIM + lane * 4);
    const float4 xv = *(const float4*)(x + (size_t)row * D_DIM + lane * 4);
    float* o = out + 1 + (size_t)row * D_DIM + lane * 4;  // +1: loss is out[0]
    o[0] = e.x; o[1] = e.y; o[2] = e.z; o[3] = e.w;
    lsum += fabsf(e.x - xv.x) + fabsf(e.y - xv.y) + fabsf(e.z - xv.z) +
            fabsf(e.w - xv.w);
  }
#pragma unroll
  for (int m = 32; m >= 1; m >>= 1) lsum += __shfl_xor(lsum, m, 64);
  if (lane == 0)
    atomicAdd(lossacc, (unsigned long long)((double)lsum * 16777216.0));
}

__global__ void vq_fin(const unsigned long long* __restrict__ lossacc,
                       float* __restrict__ out) {
  if (threadIdx.x == 0)
    out[0] = (float)((double)*lossacc * (1.0 / 16777216.0) / 8388608.0);
}

// ---------------------------------------------------------------------------
extern "C" void kernel_launch(void* const* d_in, const int* in_sizes, int n_in,
                              void* d_out, int out_size, void* d_ws, size_t ws_size,
                              hipStream_t stream) {
  const float* x = (const float*)d_in[0];
  const float* cb = (const float*)d_in[1];
  const int N = in_sizes[0] / D_DIM;  // 32768 rows

  char* ws = (char*)d_ws;
  unsigned long long* amin = (unsigned long long*)ws;                 // N*8 B
  unsigned long long* lossacc = (unsigned long long*)(ws + (size_t)N * 8);
  float* cnorm = (float*)(ws + (size_t)N * 8 + 1024);                 // K*4 B
  char* cbbT = ws + (size_t)N * 8 + 1024 + (size_t)K_CODES * 4;       // 4 MB

  hipMemsetAsync(amin, 0xFF, (size_t)N * 8, stream);  // u64 max
  hipMemsetAsync(lossacc, 0, 8, stream);

  vq_prepT<<<(32 * K_CODES) / 256, 256, 0, stream>>>(cb, (uint4*)cbbT);
  vq_norm<<<K_CODES / 4, 256, 0, stream>>>(cb, cnorm);
  vq_main<<<(N / BM) * KSPLIT, 256, 0, stream>>>(x, cbbT, cnorm, amin);
  vq_gather<<<N / 64, 256, 0, stream>>>(x, cb, amin, (float*)d_out, lossacc);
  vq_fin<<<1, 64, 0, stream>>>(lossacc, (float*)d_out);
}

// Round 3
// 124.071 us; speedup vs baseline: 2.2602x; 2.2602x over previous
//
#include <hip/hip_runtime.h>
#include <stdint.h>

#define D_DIM 256
#define K_CODES 8192
#define BM 256                   // rows per block (4 waves x 64 rows)
#define BN 64                    // codes per LDS tile
#define KSPLIT 8                 // blockIdx&7 == XCD == codebook slice
#define CPB (K_CODES / KSPLIT)   // 1024 codes per block
#define NT (CPB / BN)            // 16 tiles

typedef float f32x4 __attribute__((ext_vector_type(4)));
typedef int i32x4 __attribute__((ext_vector_type(4)));
typedef int i32x8 __attribute__((ext_vector_type(8)));
typedef __attribute__((address_space(3))) uint32_t lds_u32_t;
typedef __attribute__((address_space(1))) uint32_t glb_u32_t;

#define SCALE1 0x7F7F7F7F  // e8m0 127 = 1.0 in every byte (opsel-proof)

// ---------------------------------------------------------------------------
// prep: one wave per code.
//   cbb8[code][256B] = fp8_e4m3(-512 * c), 16B-slots XOR-swizzled by (code&15)
//   cnorm[code] = 256*||c||^2 - 1024   (MFMA C-in; keeps all scores negative)
// ---------------------------------------------------------------------------
__global__ void vq_prep(const float* __restrict__ cb, float* __restrict__ cnorm,
                        uint32_t* __restrict__ cbb8) {
  const int lane = threadIdx.x & 63;
  const int code = (blockIdx.x * blockDim.x + threadIdx.x) >> 6;
  const float4 v = *(const float4*)(cb + (size_t)code * D_DIM + lane * 4);
  float ss = v.x * v.x + v.y * v.y + v.z * v.z + v.w * v.w;
#pragma unroll
  for (int m = 32; m >= 1; m >>= 1) ss += __shfl_xor(ss, m, 64);
  if (lane == 0) cnorm[code] = 256.0f * ss - 1024.0f;
  int w = __builtin_amdgcn_cvt_pk_fp8_f32(-512.0f * v.x, -512.0f * v.y, 0, false);
  w = __builtin_amdgcn_cvt_pk_fp8_f32(-512.0f * v.z, -512.0f * v.w, w, true);
  const int slot = (lane >> 2) ^ (code & 15);  // 16B-slot swizzle
  cbb8[code * 64 + slot * 4 + (lane & 3)] = (uint32_t)w;
}

// ---------------------------------------------------------------------------
// main: MX-fp8 distance GEMM + in-mantissa argmin.
// acc = sum fp8(x) * fp8(-512 c) + (256||c||^2 - 1024) = 256*score - 1024 < 0.
// Epilogue per score: 2 insts (and_or stomp idx into low 13 bits, min_f32).
// ---------------------------------------------------------------------------
__global__ __launch_bounds__(256, 3) void vq_main(
    const float* __restrict__ x, const uint32_t* __restrict__ cbb8,
    const float* __restrict__ cnorm, uint32_t* __restrict__ amin) {
  __shared__ char lds[2 * 16384 + 4096];  // 2 B-buffers + cnorm slice
  const int tid = threadIdx.x;
  const int lane = tid & 63;
  const int wid = tid >> 6;
  const int ks = blockIdx.x & (KSPLIT - 1);
  const int mb = blockIdx.x >> 3;
  const int r0 = mb * BM + wid * 64;

  const char* cbk = (const char*)cbb8 + (size_t)ks * CPB * D_DIM;

  // stage cnorm slice (4KB) + B tile 0 (16KB)
  __builtin_amdgcn_global_load_lds(
      (glb_u32_t*)((const char*)(cnorm + ks * CPB) + tid * 16),
      (lds_u32_t*)(lds + 32768 + tid * 16), 16, 0, 0);
#pragma unroll
  for (int i = 0; i < 4; i++)
    __builtin_amdgcn_global_load_lds((glb_u32_t*)(cbk + tid * 16 + i * 4096),
                                     (lds_u32_t*)(lds + tid * 16 + i * 4096),
                                     16, 0, 0);

  // A fragments: fp8(x). lane: row (lane&15), k = (lane>>4)*32 + t*128 + [0,32)
  i32x8 a[4][2];
#pragma unroll
  for (int rf = 0; rf < 4; rf++)
#pragma unroll
    for (int t = 0; t < 2; t++) {
      const float* xr = x + (size_t)(r0 + rf * 16 + (lane & 15)) * D_DIM +
                        (lane >> 4) * 32 + t * 128;
      i32x8 fr;
#pragma unroll
      for (int d = 0; d < 8; d++) {
        const float4 f = *(const float4*)(xr + d * 4);
        int u = __builtin_amdgcn_cvt_pk_fp8_f32(f.x, f.y, 0, false);
        u = __builtin_amdgcn_cvt_pk_fp8_f32(f.z, f.w, u, true);
        fr[d] = u;
      }
      a[rf][t] = fr;
    }

  float mv[16];
#pragma unroll
  for (int i = 0; i < 16; i++) mv[i] = 0.0f;  // scores are all negative

  uint32_t colv = (uint32_t)(ks * CPB + (lane & 15));
  const int key16 = (lane & 15) << 4;
  const int lanebase = (lane & 15) * 256;
  const int g32 = (lane >> 4) * 32;

  asm volatile("s_waitcnt vmcnt(0)" ::: "memory");
  __syncthreads();

  for (int tile = 0; tile < NT; tile++) {
    const int cur = tile & 1;
    if (tile + 1 < NT) {
      const char* src = cbk + (size_t)(tile + 1) * 16384;
#pragma unroll
      for (int i = 0; i < 4; i++)
        __builtin_amdgcn_global_load_lds(
            (glb_u32_t*)(src + tid * 16 + i * 4096),
            (lds_u32_t*)(lds + (cur ^ 1) * 16384 + tid * 16 + i * 4096), 16, 0,
            0);
    }
    // 4 swizzled B addresses (t,b combos); s adds a compile-time 4096*s
    int badr[4];
#pragma unroll
    for (int t = 0; t < 2; t++)
#pragma unroll
      for (int b = 0; b < 2; b++)
        badr[t * 2 + b] =
            cur * 16384 + lanebase + (((t * 128 + g32 + b * 16)) ^ key16);

    float cnv[4];
#pragma unroll
    for (int s = 0; s < 4; s++)
      cnv[s] = *(const float*)(lds + 32768 + tile * 256 + s * 64 +
                               (lane & 15) * 4);

#pragma unroll
    for (int s = 0; s < 4; s++) {
      const f32x4 cc = {cnv[s], cnv[s], cnv[s], cnv[s]};
      i32x4 lo = *(const i32x4*)(lds + badr[0] + s * 4096);
      i32x4 hi = *(const i32x4*)(lds + badr[1] + s * 4096);
      const i32x8 b0 = __builtin_shufflevector(lo, hi, 0, 1, 2, 3, 4, 5, 6, 7);
      f32x4 acc0 = __builtin_amdgcn_mfma_scale_f32_16x16x128_f8f6f4(
          a[0][0], b0, cc, 0, 0, 0, SCALE1, 0, SCALE1);
      f32x4 acc1 = __builtin_amdgcn_mfma_scale_f32_16x16x128_f8f6f4(
          a[1][0], b0, cc, 0, 0, 0, SCALE1, 0, SCALE1);
      f32x4 acc2 = __builtin_amdgcn_mfma_scale_f32_16x16x128_f8f6f4(
          a[2][0], b0, cc, 0, 0, 0, SCALE1, 0, SCALE1);
      f32x4 acc3 = __builtin_amdgcn_mfma_scale_f32_16x16x128_f8f6f4(
          a[3][0], b0, cc, 0, 0, 0, SCALE1, 0, SCALE1);
      lo = *(const i32x4*)(lds + badr[2] + s * 4096);
      hi = *(const i32x4*)(lds + badr[3] + s * 4096);
      const i32x8 b1 = __builtin_shufflevector(lo, hi, 0, 1, 2, 3, 4, 5, 6, 7);
      acc0 = __builtin_amdgcn_mfma_scale_f32_16x16x128_f8f6f4(
          a[0][1], b1, acc0, 0, 0, 0, SCALE1, 0, SCALE1);
      acc1 = __builtin_amdgcn_mfma_scale_f32_16x16x128_f8f6f4(
          a[1][1], b1, acc1, 0, 0, 0, SCALE1, 0, SCALE1);
      acc2 = __builtin_amdgcn_mfma_scale_f32_16x16x128_f8f6f4(
          a[2][1], b1, acc2, 0, 0, 0, SCALE1, 0, SCALE1);
      acc3 = __builtin_amdgcn_mfma_scale_f32_16x16x128_f8f6f4(
          a[3][1], b1, acc3, 0, 0, 0, SCALE1, 0, SCALE1);

      const f32x4 av[4] = {acc0, acc1, acc2, acc3};
#pragma unroll
      for (int rf = 0; rf < 4; rf++)
#pragma unroll
        for (int j = 0; j < 4; j++) {
          uint32_t sb = __builtin_bit_cast(uint32_t, av[rf][j]);
          sb = (sb & 0xFFFFE000u) | colv;  // v_and_or_b32: idx in mantissa
          const float sv = __builtin_bit_cast(float, sb);
          mv[rf * 4 + j] = fminf(mv[rf * 4 + j], sv);
        }
      colv += 16;
    }
    asm volatile("s_waitcnt vmcnt(0)" ::: "memory");
    __syncthreads();
  }

  // reduce the 16 code-lanes per row; merge globally (neg floats: u32 max)
#pragma unroll
  for (int rf = 0; rf < 4; rf++)
#pragma unroll
    for (int j = 0; j < 4; j++) {
      float m = mv[rf * 4 + j];
#pragma unroll
      for (int d = 1; d < 16; d <<= 1) m = fminf(m, __shfl_xor(m, d, 64));
      if ((lane & 15) == 0) {
        const int row = r0 + rf * 16 + (lane >> 4) * 4 + j;
        atomicMax(&amin[row], __builtin_bit_cast(uint32_t, m));
      }
    }
}

// ---------------------------------------------------------------------------
// gather: x_q = codebook[idx] (exact f32 rows), L1 loss via fixed-point atomic
// ---------------------------------------------------------------------------
__global__ void vq_gather(const float* __restrict__ x, const float* __restrict__ cb,
                          const uint32_t* __restrict__ amin,
                          float* __restrict__ out,
                          unsigned long long* __restrict__ lossacc) {
  const int lane = threadIdx.x & 63;
  const int wid = threadIdx.x >> 6;
  const int row0 = blockIdx.x * 64 + wid * 16;
  float lsum = 0.f;
  for (int r = 0; r < 16; r++) {
    const int row = row0 + r;
    const uint32_t idx = amin[row] & 8191u;
    const float4 e = *(const float4*)(cb + (size_t)idx * D_DIM + lane * 4);
    const float4 xv = *(const float4*)(x + (size_t)row * D_DIM + lane * 4);
    float* o = out + 1 + (size_t)row * D_DIM + lane * 4;  // out[0] = loss
    o[0] = e.x; o[1] = e.y; o[2] = e.z; o[3] = e.w;
    lsum += fabsf(e.x - xv.x) + fabsf(e.y - xv.y) + fabsf(e.z - xv.z) +
            fabsf(e.w - xv.w);
  }
#pragma unroll
  for (int m = 32; m >= 1; m >>= 1) lsum += __shfl_xor(lsum, m, 64);
  if (lane == 0)
    atomicAdd(lossacc, (unsigned long long)((double)lsum * 16777216.0));
}

__global__ void vq_fin(const unsigned long long* __restrict__ lossacc,
                       float* __restrict__ out) {
  if (threadIdx.x == 0)
    out[0] = (float)((double)*lossacc * (1.0 / 16777216.0) / 8388608.0);
}

// ---------------------------------------------------------------------------
extern "C" void kernel_launch(void* const* d_in, const int* in_sizes, int n_in,
                              void* d_out, int out_size, void* d_ws, size_t ws_size,
                              hipStream_t stream) {
  const float* x = (const float*)d_in[0];
  const float* cb = (const float*)d_in[1];
  const int N = in_sizes[0] / D_DIM;  // 32768 rows

  char* ws = (char*)d_ws;
  uint32_t* amin = (uint32_t*)ws;                                   // N*4 B
  unsigned long long* lossacc = (unsigned long long*)(ws + (size_t)N * 4);
  float* cnorm = (float*)(ws + (size_t)N * 4 + 1024);               // K*4 B
  uint32_t* cbb8 =
      (uint32_t*)(ws + (size_t)N * 4 + 1024 + (size_t)K_CODES * 4); // K*256 B

  hipMemsetAsync(amin, 0, (size_t)N * 4, stream);  // packed scores have sign bit
  hipMemsetAsync(lossacc, 0, 8, stream);

  vq_prep<<<K_CODES / 4, 256, 0, stream>>>(cb, cnorm, cbb8);
  vq_main<<<(N / BM) * KSPLIT, 256, 0, stream>>>(x, cbb8, cnorm, amin);
  vq_gather<<<N / 64, 256, 0, stream>>>(x, cb, amin, (float*)d_out, lossacc);
  vq_fin<<<1, 64, 0, stream>>>(lossacc, (float*)d_out);
}